// Round 4
// baseline (1311.261 us; speedup 1.0000x reference)
//
#include <hip/hip_runtime.h>
#include <stdint.h>

// QuantLinear: x[4,2048,4096] fp32, int4-packed W [11008,4096], group=128.
// (1) per-token int8 fake-quant  (2) int4 -> int8 unpack  (3) i8 MFMA GEMM,
// 256x256 tile, BK=64, 4 rotating LDS buffers, counted vmcnt(4), per-K-tile
// fp32 group-scale accumulate, f16 scales in LDS, XCD-swizzled grid.

#define IN_F 4096
#define OUT_F 11008

#define BM 256
#define BN 256
#define BK 64
#define NT (IN_F / BK)         // 64 K-tiles
#define NG 32                  // 32 quant groups (GS=128 = 2 K-tiles)
#define BUFSZ (BM * BK)        // 16384 B per A (or B) buffer

using i32x2 = __attribute__((ext_vector_type(2))) int;
using i32x4 = __attribute__((ext_vector_type(4))) int;
using f32x4 = __attribute__((ext_vector_type(4))) float;

// ---------------- Kernel 1: per-token activation fake-quant ----------------
__global__ __launch_bounds__(256) void act_quant_kernel(
    const float* __restrict__ x, int8_t* __restrict__ q, float* __restrict__ sc) {
  __shared__ float wmax[4];
  const int tok = blockIdx.x;
  const int tid = threadIdx.x;
  const float* xr = x + (size_t)tok * IN_F;

  f32x4 v[4];
  float am = 0.f;
#pragma unroll
  for (int i = 0; i < 4; ++i) {
    v[i] = *(const f32x4*)(xr + i * 1024 + tid * 4);   // lane-contiguous 16B
#pragma unroll
    for (int j = 0; j < 4; ++j) am = fmaxf(am, fabsf(v[i][j]));
  }
#pragma unroll
  for (int off = 1; off < 64; off <<= 1) am = fmaxf(am, __shfl_xor(am, off));
  if ((tid & 63) == 0) wmax[tid >> 6] = am;
  __syncthreads();
  am = fmaxf(fmaxf(wmax[0], wmax[1]), fmaxf(wmax[2], wmax[3]));
  const float scale = fmaxf(am, 1e-5f) / 127.0f;

#pragma unroll
  for (int i = 0; i < 4; ++i) {
    uint32_t w = 0;
#pragma unroll
    for (int j = 0; j < 4; ++j) {
      float r = rintf(v[i][j] / scale);          // round-half-even == jnp.round
      r = fminf(fmaxf(r, -128.f), 127.f);
      int iv = (int)r;
      w |= (uint32_t)(iv & 255) << (8 * j);
    }
    *(uint32_t*)(q + (size_t)tok * IN_F + i * 1024 + tid * 4) = w;
  }
  if (tid == 0) sc[tok] = scale;
}

// ---------------- Kernel 2: unpack int4 -> int8 (nibble - zero) ----------------
// One byte per int32. Thread t handles 4 int32 = 8 weights (lane-contiguous 16B read, 8B write).
__global__ __launch_bounds__(256) void unpack_kernel(
    const int* __restrict__ qw, const int* __restrict__ wz, int8_t* __restrict__ w8) {
  const int t = blockIdx.x * 256 + threadIdx.x;      // 0 .. 5,636,095
  const int z = wz[t >> 4];                          // weights 8t..8t+7, group = t/16
  const i32x4 a = *(const i32x4*)(qw + (size_t)t * 4);
  i32x2 o;
#pragma unroll
  for (int h = 0; h < 2; ++h) {
    const int x0 = a[2 * h], x1 = a[2 * h + 1];
    const int w0 = ((x0 >> 4) & 15) - z;
    const int w1 = (x0 & 15) - z;
    const int w2 = ((x1 >> 4) & 15) - z;
    const int w3 = (x1 & 15) - z;
    o[h] = (w0 & 255) | ((w1 & 255) << 8) | ((w2 & 255) << 16) | ((w3 & 255) << 24);
  }
  *(i32x2*)(w8 + (size_t)t * 8) = o;
}

// ---------------- Kernel 3: i8 GEMM, 256x256, 4-buffer counted-vmcnt pipeline ----
// A = q8 [M][K], B = w8 [N][K] (row-major, K contiguous). 8 waves: wm=(wid>>2)*128,
// wn=(wid&3)*64. Per K-tile (BK=64): 4 phases (quadrants qm,qn), each 8 MFMA + scale.
// LDS swizzle: 16B slot ks stored at ks ^ ((row>>1)&3)  (2-way banks = free).
__global__ __launch_bounds__(512, 2) void gemm_kernel(
    const int8_t* __restrict__ Aq, const int8_t* __restrict__ Bq,
    const float* __restrict__ asc, const float* __restrict__ wsc,
    const float* __restrict__ bias, float* __restrict__ out) {
  __shared__ int8_t As_l[4 * BUFSZ];     // 64 KiB
  __shared__ int8_t Bs_l[4 * BUFSZ];     // 64 KiB
  __shared__ _Float16 Wsh[NG * BN];      // 16 KiB: Wsh[g][col]

  const int tid = threadIdx.x;
  const int lane = tid & 63;
  const int wid = tid >> 6;

  // XCD-aware bijective swizzle: 1376 blocks = 8 * 172
  const int bid = blockIdx.x;
  const int swz = (bid & 7) * 172 + (bid >> 3);
  const int bm0 = (swz / 43) * BM;
  const int bn0 = (swz % 43) * BN;

  const int wm = (wid >> 2) * 128;
  const int wn = (wid & 3) * 64;
  const int cl = lane & 15;
  const int ksw = ((lane >> 4) ^ ((cl >> 1) & 3)) * 16;
  const int regA = (wm + cl) * BK + ksw;
  const int regB = (wn + cl) * BK + ksw;

  const int8_t* Abase = Aq + (size_t)bm0 * IN_F;
  const int8_t* Bbase = Bq + (size_t)bn0 * IN_F;

  // ---- prologue: stage group scales (f32 -> f16, transposed) ----
  {
    const int c = tid >> 1, g0 = (tid & 1) * 16;
    const float* src = wsc + (size_t)(bn0 + c) * NG + g0;
#pragma unroll
    for (int k = 0; k < 16; k += 4) {
      f32x4 v = *(const f32x4*)(src + k);
#pragma unroll
      for (int e = 0; e < 4; ++e) Wsh[(g0 + k + e) * BN + c] = (_Float16)v[e];
    }
  }

  // stage unit: half h (128 rows x 64B = 8KB) of tile st into lbuf.
  // dest linear (wave-uniform base + lane*16); SOURCE pre-swizzled.
#define STAGE(gbase, st, h, lbuf) do {                                         \
    const int _row = (h) * 128 + (tid >> 2);                                   \
    const int _ck = (tid & 3) ^ ((tid >> 3) & 3);                              \
    __builtin_amdgcn_global_load_lds(                                          \
      (const __attribute__((address_space(1))) void*)(                         \
          (gbase) + (size_t)_row * IN_F + (st) * BK + _ck * 16),               \
      (__attribute__((address_space(3))) void*)(                               \
          (lbuf) + (h) * 8192 + wid * 1024), 16, 0, 0);                        \
  } while (0)

  // ---- prologue: stage tiles 0 and 1 ----
  STAGE(Abase, 0, 0, As_l); STAGE(Abase, 0, 1, As_l);
  STAGE(Bbase, 0, 0, Bs_l); STAGE(Bbase, 0, 1, Bs_l);
  STAGE(Abase, 1, 0, As_l + BUFSZ); STAGE(Abase, 1, 1, As_l + BUFSZ);
  STAGE(Bbase, 1, 0, Bs_l + BUFSZ); STAGE(Bbase, 1, 1, Bs_l + BUFSZ);
  __syncthreads();                       // full drain (vmcnt 0 + lgkm 0) once

  f32x4 facc[8][4] = {};
  const i32x4 izero = {0, 0, 0, 0};

  // phase: quadrant (QM,QN) of tile t; one optional stage; 8 MFMA + scale.
#define PHASE(QM, QN, STAGE_STMT) do {                                         \
    STAGE_STMT;                                                                \
    i32x4 af[4], bf[2];                                                        \
    _Float16 wh0 = Wsh[g * BN + wn + ((QN) * 2 + 0) * 16 + cl];                \
    _Float16 wh1 = Wsh[g * BN + wn + ((QN) * 2 + 1) * 16 + cl];                \
    _Pragma("unroll")                                                          \
    for (int i = 0; i < 4; ++i)                                                \
      af[i] = *(const i32x4*)(ab + regA + ((QM) * 4 + i) * 1024);              \
    bf[0] = *(const i32x4*)(bb + regB + ((QN) * 2 + 0) * 1024);                \
    bf[1] = *(const i32x4*)(bb + regB + ((QN) * 2 + 1) * 1024);                \
    __builtin_amdgcn_s_setprio(1);                                             \
    const float w0 = (float)wh0, w1 = (float)wh1;                              \
    _Pragma("unroll")                                                          \
    for (int i = 0; i < 4; ++i) {                                              \
      i32x4 t0 = __builtin_amdgcn_mfma_i32_16x16x64_i8(af[i], bf[0], izero, 0, 0, 0); \
      i32x4 t1 = __builtin_amdgcn_mfma_i32_16x16x64_i8(af[i], bf[1], izero, 0, 0, 0); \
      _Pragma("unroll")                                                        \
      for (int e = 0; e < 4; ++e) {                                            \
        facc[(QM) * 4 + i][(QN) * 2 + 0][e] += w0 * (float)t0[e];              \
        facc[(QM) * 4 + i][(QN) * 2 + 1][e] += w1 * (float)t1[e];              \
      }                                                                        \
    }                                                                          \
    __builtin_amdgcn_s_setprio(0);                                             \
  } while (0)

  for (int t = 0; t < NT; ++t) {
    const int8_t* ab = As_l + (t & 3) * BUFSZ;
    const int8_t* bb = Bs_l + (t & 3) * BUFSZ;
    int8_t* sa = As_l + ((t + 2) & 3) * BUFSZ;
    int8_t* sb = Bs_l + ((t + 2) & 3) * BUFSZ;
    const int g = t >> 1;
    const bool dost = (t + 2) < NT;

    PHASE(0, 0, if (dost) STAGE(Abase, t + 2, 0, sa));
    PHASE(0, 1, if (dost) STAGE(Abase, t + 2, 1, sa));
    PHASE(1, 0, if (dost) STAGE(Bbase, t + 2, 0, sb));
    PHASE(1, 1, if (dost) STAGE(Bbase, t + 2, 1, sb));

    // counted drain: keep tile t+2's 4 loads in flight, tile t+1 fully landed.
    asm volatile("s_waitcnt vmcnt(4)" ::: "memory");
    __builtin_amdgcn_s_barrier();
  }

  // ---- epilogue: out = asc[m] * facc + bias[n] ----
  const int r0 = (lane >> 4) * 4;
#pragma unroll
  for (int i = 0; i < 8; ++i) {
    const int mrow = bm0 + wm + i * 16 + r0;
    f32x4 a4 = *(const f32x4*)(asc + mrow);
#pragma unroll
    for (int e = 0; e < 4; ++e) {
      float* orow = out + (size_t)(mrow + e) * OUT_F + bn0 + wn + cl;
#pragma unroll
      for (int j = 0; j < 4; ++j)
        orow[j * 16] = facc[i][j][e] * a4[e] + bias[bn0 + wn + j * 16 + cl];
    }
  }
#undef PHASE
#undef STAGE
}

extern "C" void kernel_launch(void* const* d_in, const int* in_sizes, int n_in,
                              void* d_out, int out_size, void* d_ws, size_t ws_size,
                              hipStream_t stream) {
  const float* x = (const float*)d_in[0];
  const int* qw = (const int*)d_in[1];
  const float* wsc = (const float*)d_in[2];
  const int* wz = (const int*)d_in[3];
  const float* bias = (const float*)d_in[4];
  float* out = (float*)d_out;

  const int tokens = in_sizes[0] / IN_F;  // 8192

  int8_t* w8 = (int8_t*)d_ws;
  int8_t* q8 = w8 + (size_t)OUT_F * IN_F;
  float* sc = (float*)(q8 + (size_t)tokens * IN_F);

  act_quant_kernel<<<tokens, 256, 0, stream>>>(x, q8, sc);
  unpack_kernel<<<(OUT_F * IN_F / 2 / 4) / 256, 256, 0, stream>>>(qw, wz, w8);
  gemm_kernel<<<(tokens / BM) * (OUT_F / BN), 512, 0, stream>>>(q8, w8, sc, wsc, bias, out);
}